// Round 24
// baseline (487.763 us; speedup 1.0000x reference)
//
#include <hip/hip_runtime.h>
#include <cstdint>

#define B_ 64
#define N_ 4096
#define D_ 256
#define NS_ 8
#define HID_ 512
#define TOK_ 128
#define NPART_ 32
#define EPS_ 1e-8f
#define SCALE_ 0.0625f
#define LN_EPS_ 1e-5f

typedef _Float16 f16;
typedef __attribute__((ext_vector_type(2))) _Float16 f16x2;
typedef __attribute__((ext_vector_type(4))) _Float16 f16x4;
typedef __attribute__((ext_vector_type(8))) _Float16 f16x8;
typedef __attribute__((ext_vector_type(4))) float f32x4;

#define MFMA16(a, b, c) __builtin_amdgcn_mfma_f32_16x16x32_f16(a, b, c, 0, 0, 0)
#define GLOAD_LDS16(g, l) __builtin_amdgcn_global_load_lds( \
    (const __attribute__((address_space(1))) void*)(g),     \
    (__attribute__((address_space(3))) void*)(l), 16, 0, 0)

// ---- merged setup: xh LN-cast | GRU gate pack | slots | w1/w2 pack ----
__global__ __launch_bounds__(256) void k_setup(
    const float* __restrict__ in, const float* __restrict__ gin,
    const float* __restrict__ bin, f16* __restrict__ xh,
    const float* __restrict__ wi, const float* __restrict__ wh,
    f16* __restrict__ gwp,
    const float* __restrict__ noise, const float* __restrict__ mu,
    const float* __restrict__ ls, float* __restrict__ slots,
    const float* __restrict__ w1, const float* __restrict__ w2,
    f16* __restrict__ w1p, f16* __restrict__ w2p) {
  const int blk = blockIdx.x;
  const int t = threadIdx.x;
  if (blk < 65536) {
    const int wave = t >> 6, lane = t & 63;
    const size_t row = (size_t)blk * 4 + wave;
    const float* r = in + row * D_;
    float4 a = *(const float4*)(r + lane * 4);
    float s1 = a.x + a.y + a.z + a.w;
    float s2 = a.x * a.x + a.y * a.y + a.z * a.z + a.w * a.w;
    #pragma unroll
    for (int m = 32; m >= 1; m >>= 1) { s1 += __shfl_xor(s1, m, 64); s2 += __shfl_xor(s2, m, 64); }
    const float mean = s1 * (1.f / D_);
    const float rstd = rsqrtf(s2 * (1.f / D_) - mean * mean + LN_EPS_);
    float4 gg = *(const float4*)(gin + lane * 4);
    float4 bv = *(const float4*)(bin + lane * 4);
    f16x4 o;
    o[0] = (f16)((a.x - mean) * rstd * gg.x + bv.x);
    o[1] = (f16)((a.y - mean) * rstd * gg.y + bv.y);
    o[2] = (f16)((a.z - mean) * rstd * gg.z + bv.z);
    o[3] = (f16)((a.w - mean) * rstd * gg.w + bv.w);
    *(f16x4*)(xh + row * D_ + lane * 4) = o;
  } else if (blk < 65792) {
    // GRU gate pack: d = blk-65536, cell (d,t) -> f16x8 {wi r/z/n, wh r/z/n, 0,0}
    const int d = blk - 65536;
    f16x8 p;
    p[0] = (f16)wi[(size_t)(t)       * 256 + d];
    p[1] = (f16)wi[(size_t)(256 + t) * 256 + d];
    p[2] = (f16)wi[(size_t)(512 + t) * 256 + d];
    p[3] = (f16)wh[(size_t)(t)       * 256 + d];
    p[4] = (f16)wh[(size_t)(256 + t) * 256 + d];
    p[5] = (f16)wh[(size_t)(512 + t) * 256 + d];
    p[6] = (f16)0.f; p[7] = (f16)0.f;
    *(f16x8*)&gwp[((size_t)d * 256 + t) * 8] = p;
  } else if (blk < 66304) {
    const int idx = (blk - 65792) * 256 + t;
    const int d = idx & 255;
    slots[idx] = mu[d] + __expf(ls[d]) * noise[idx];
  } else if (blk < 66560) {
    // w1 pack: row d, cols (t, 256+t)
    const int d = blk - 66304;
    f16x2 p;
    p[0] = (f16)w1[(size_t)d * HID_ + t];
    p[1] = (f16)w1[(size_t)d * HID_ + 256 + t];
    *(f16x2*)&w1p[((size_t)d * 256 + t) * 2] = p;
  } else {
    // w2 pack: row pair (2dd, 2dd+1), col t
    const int dd = blk - 66560;
    f16x2 p;
    p[0] = (f16)w2[(size_t)(2 * dd)     * D_ + t];
    p[1] = (f16)w2[(size_t)(2 * dd + 1) * D_ + t];
    *(f16x2*)&w2p[((size_t)dd * 256 + t) * 2] = p;
  }
}

// ---- M[c][e] = SCALE * sum_d Wq[c][d] * Wk[e][d]  (direct, no transpose) ----
__global__ __launch_bounds__(256) void k_m(const float* __restrict__ Wq,
                                           const float* __restrict__ Wk,
                                           float* __restrict__ M) {
  __shared__ float wq[256];
  const int c = blockIdx.x, e = threadIdx.x;
  wq[e] = Wq[c * 256 + e];
  __syncthreads();
  const float* wk = Wk + (size_t)e * 256;   // per-thread contiguous row
  float a0 = 0.f, a1 = 0.f, a2 = 0.f, a3 = 0.f;
  #pragma unroll 8
  for (int d = 0; d < 256; d += 4) {
    float4 w = *(const float4*)(wk + d);
    a0 = fmaf(wq[d],     w.x, a0);
    a1 = fmaf(wq[d + 1], w.y, a1);
    a2 = fmaf(wq[d + 2], w.z, a2);
    a3 = fmaf(wq[d + 3], w.w, a3);
  }
  M[c * 256 + e] = (a0 + a1 + a2 + a3) * SCALE_;
}

// ---- qkh = f16( LN(slots) @ M )  (once, before iter 0) ----
__global__ __launch_bounds__(256) void k_qk(const float* __restrict__ slots,
    const float* __restrict__ g, const float* __restrict__ b,
    const float* __restrict__ M, f16* __restrict__ qkh) {
  const int row = blockIdx.x;
  const int t = threadIdx.x;
  __shared__ float sl[256];
  __shared__ float red1[4], red2[4];
  float val = slots[(size_t)row * D_ + t];
  float s1 = val, s2 = val * val;
  #pragma unroll
  for (int m = 32; m >= 1; m >>= 1) { s1 += __shfl_xor(s1, m, 64); s2 += __shfl_xor(s2, m, 64); }
  int wave = t >> 6, lane = t & 63;
  if (lane == 0) { red1[wave] = s1; red2[wave] = s2; }
  __syncthreads();
  s1 = red1[0] + red1[1] + red1[2] + red1[3];
  s2 = red2[0] + red2[1] + red2[2] + red2[3];
  float mean = s1 * (1.f / D_);
  float rstd = rsqrtf(s2 * (1.f / D_) - mean * mean + LN_EPS_);
  sl[t] = (val - mean) * rstd * g[t] + b[t];
  __syncthreads();
  float a0 = 0.f, a1 = 0.f, a2 = 0.f, a3 = 0.f;
  #pragma unroll 8
  for (int d = 0; d < D_; d += 4) {
    a0 = fmaf(sl[d],     M[(d)     * D_ + t], a0);
    a1 = fmaf(sl[d + 1], M[(d + 1) * D_ + t], a1);
    a2 = fmaf(sl[d + 2], M[(d + 2) * D_ + t], a2);
    a3 = fmaf(sl[d + 3], M[(d + 3) * D_ + t], a3);
  }
  qkh[((size_t)(row >> 3) * 16 + (row & 7)) * D_ + t] = (f16)(a0 + a1 + a2 + a3);
}

// ---- MFMA attention -> partials, 256 thr, TOK_=128 (R23 config) ----
__global__ __launch_bounds__(256) void k_attn_upd(
    const f16* __restrict__ xh, const f16* __restrict__ qkh,
    float* __restrict__ urp, float* __restrict__ asp) {
  __shared__ __align__(16) f16 xt[TOK_ * 256];      // 64 KB
  __shared__ __align__(16) f16 qs[16 * 256];        // 8 KB
  __shared__ __align__(16) float wv_s[NS_ * TOK_];  // 4 KB, [slot][token]
  const int b = blockIdx.y;
  const int blkx = blockIdx.x;
  const int jt = blkx * TOK_;
  const int part = b * NPART_ + blkx;
  const int tid = threadIdx.x;
  const int wave = tid >> 6, lane = tid & 63;

  {
    const f16* src = xh + ((size_t)b * N_ + jt) * D_;
    #pragma unroll
    for (int i = 0; i < 16; ++i) {
      const int r = i * 8 + (tid >> 5), c = tid & 31;
      GLOAD_LDS16(src + r * 256 + ((c ^ (r & 7)) * 8), &xt[r * 256 + c * 8]);
    }
  }
  {
    const int r = tid >> 4, c0 = (tid & 15) * 2;
    const f16* src = qkh + ((size_t)b * 16 + r) * D_;
    *(f16x8*)&qs[r * 256 + ((c0)     ^ (r & 7)) * 8] = *(const f16x8*)(src + c0 * 8);
    *(f16x8*)&qs[r * 256 + ((c0 + 1) ^ (r & 7)) * 8] = *(const f16x8*)(src + c0 * 8 + 8);
  }
  __syncthreads();

  const int kg = lane >> 4;
  f16x8 afr[8];
  {
    const int arow = lane & 15;
    #pragma unroll
    for (int kk = 0; kk < 8; ++kk)
      afr[kk] = *(const f16x8*)&qs[arow * 256 + ((kk * 4 + kg) ^ (arow & 7)) * 8];
  }
  #pragma unroll
  for (int t2 = 0; t2 < 2; ++t2) {
    const int nt = wave * 2 + t2;
    const int tok = nt * 16 + (lane & 15);
    f32x4 acc = {0.f, 0.f, 0.f, 0.f};
    #pragma unroll
    for (int kk = 0; kk < 8; ++kk) {
      f16x8 bf = *(const f16x8*)&xt[tok * 256 + ((kk * 4 + kg) ^ (tok & 7)) * 8];
      acc = MFMA16(afr[kk], bf, acc);
    }
    float o0 = __shfl_xor(acc[0], 16, 64);
    float o1 = __shfl_xor(acc[1], 16, 64);
    float o2 = __shfl_xor(acc[2], 16, 64);
    float o3 = __shfl_xor(acc[3], 16, 64);
    if (lane < 32) {
      float m = fmaxf(fmaxf(fmaxf(acc[0], acc[1]), fmaxf(acc[2], acc[3])),
                      fmaxf(fmaxf(o0, o1), fmaxf(o2, o3)));
      float e0 = __expf(acc[0] - m), e1 = __expf(acc[1] - m);
      float e2 = __expf(acc[2] - m), e3 = __expf(acc[3] - m);
      float sm = e0 + e1 + e2 + e3;
      float so = __shfl_xor(sm, 16, 64);
      float inv = 1.f / (sm + so);
      const int sb = (lane >> 4) * 4;
      wv_s[(sb + 0) * TOK_ + tok] = e0 * inv + EPS_;
      wv_s[(sb + 1) * TOK_ + tok] = e1 * inv + EPS_;
      wv_s[(sb + 2) * TOK_ + tok] = e2 * inv + EPS_;
      wv_s[(sb + 3) * TOK_ + tok] = e3 * inv + EPS_;
    }
  }
  __syncthreads();

  {
    const int i0 = wave * 2;
    const int ch0 = lane >> 1, sub = (lane & 1) * 4;
    float a0[4] = {0.f, 0.f, 0.f, 0.f};
    float a1[4] = {0.f, 0.f, 0.f, 0.f};
    float s0 = 0.f, s1 = 0.f;
    #pragma unroll 4
    for (int j4 = 0; j4 < TOK_; j4 += 4) {
      float4 w0v = *(const float4*)&wv_s[i0 * TOK_ + j4];
      float4 w1v = *(const float4*)&wv_s[(i0 + 1) * TOK_ + j4];
      s0 += w0v.x + w0v.y + w0v.z + w0v.w;
      s1 += w1v.x + w1v.y + w1v.z + w1v.w;
      float w0a[4] = {w0v.x, w0v.y, w0v.z, w0v.w};
      float w1a[4] = {w1v.x, w1v.y, w1v.z, w1v.w};
      #pragma unroll
      for (int u = 0; u < 4; ++u) {
        const int j = j4 + u;
        f16x4 v = *(const f16x4*)&xt[j * 256 + (ch0 ^ (j & 7)) * 8 + sub];
        float vx = (float)v[0], vy = (float)v[1], vz = (float)v[2], vw = (float)v[3];
        a0[0] = fmaf(w0a[u], vx, a0[0]); a0[1] = fmaf(w0a[u], vy, a0[1]);
        a0[2] = fmaf(w0a[u], vz, a0[2]); a0[3] = fmaf(w0a[u], vw, a0[3]);
        a1[0] = fmaf(w1a[u], vx, a1[0]); a1[1] = fmaf(w1a[u], vy, a1[1]);
        a1[2] = fmaf(w1a[u], vz, a1[2]); a1[3] = fmaf(w1a[u], vw, a1[3]);
      }
    }
    float* u0 = urp + ((size_t)part * NS_ + i0) * D_ + lane * 4;
    *(float4*)(u0)      = make_float4(a0[0], a0[1], a0[2], a0[3]);
    *(float4*)(u0 + D_) = make_float4(a1[0], a1[1], a1[2], a1[3]);
    if (lane == 0) {
      asp[part * NS_ + i0]     = s0;
      asp[part * NS_ + i0 + 1] = s1;
    }
  }
}

// ---- GRU + LN + MLP (+ optional next-qk); packed weights ----
__global__ __launch_bounds__(256) void k_gru_mlp(
    const float* __restrict__ urp, const float* __restrict__ asp,
    const float* __restrict__ slots, const float* __restrict__ Wv,
    const f16* __restrict__ gwp,
    const float* __restrict__ bi, const float* __restrict__ bh,
    const f16* __restrict__ w1p, const float* __restrict__ b1,
    const f16* __restrict__ w2p, const float* __restrict__ b2,
    const float* __restrict__ gf, const float* __restrict__ bf,
    const float* __restrict__ gs, const float* __restrict__ bs,
    const float* __restrict__ M, const int want_qk,
    float* __restrict__ out, f16* __restrict__ qkh) {
  const int row = blockIdx.x;
  const int bb = row >> 3, ii = row & 7;
  const int t = threadIdx.x;
  __shared__ float urs[256], xs[256], hs[256], ffs[256], hid[512];
  __shared__ float red1[4], red2[4];
  const int wave = t >> 6, lane = t & 63;
  const float hv = slots[(size_t)row * D_ + t];
  hs[t] = hv;
  {
    float usum = 0.f;
    #pragma unroll 8
    for (int p = 0; p < NPART_; ++p)
      usum += urp[((size_t)(bb * NPART_ + p) * NS_ + ii) * D_ + t];
    urs[t] = usum;
  }
  {
    float ap = (t < NPART_) ? asp[(size_t)(bb * NPART_ + t) * NS_ + ii] : 0.f;
    #pragma unroll
    for (int m = 16; m >= 1; m >>= 1) ap += __shfl_xor(ap, m, 64);
    if (t == 0) red1[0] = ap;
  }
  __syncthreads();
  const float asv = red1[0];
  {
    const float ia = 1.f / asv;
    float u0 = 0.f, u1 = 0.f, u2 = 0.f, u3 = 0.f;
    #pragma unroll 8
    for (int e = 0; e < D_; e += 4) {
      u0 = fmaf(urs[e],     Wv[(size_t)(e)     * D_ + t], u0);
      u1 = fmaf(urs[e + 1], Wv[(size_t)(e + 1) * D_ + t], u1);
      u2 = fmaf(urs[e + 2], Wv[(size_t)(e + 2) * D_ + t], u2);
      u3 = fmaf(urs[e + 3], Wv[(size_t)(e + 3) * D_ + t], u3);
    }
    xs[t] = (u0 + u1 + u2 + u3) * ia;
  }
  __syncthreads();
  float gi0 = bi[t], gi1 = bi[D_ + t], gi2 = bi[2 * D_ + t];
  float gh0 = bh[t], gh1 = bh[D_ + t], gh2 = bh[2 * D_ + t];
  #pragma unroll 4
  for (int d = 0; d < D_; ++d) {
    f16x8 wp = *(const f16x8*)&gwp[((size_t)d * 256 + t) * 8];
    float xd = xs[d], hd = hs[d];
    gi0 = fmaf(xd, (float)wp[0], gi0);
    gi1 = fmaf(xd, (float)wp[1], gi1);
    gi2 = fmaf(xd, (float)wp[2], gi2);
    gh0 = fmaf(hd, (float)wp[3], gh0);
    gh1 = fmaf(hd, (float)wp[4], gh1);
    gh2 = fmaf(hd, (float)wp[5], gh2);
  }
  float r = 1.f / (1.f + __expf(-(gi0 + gh0)));
  float z = 1.f / (1.f + __expf(-(gi1 + gh1)));
  float n = tanhf(gi2 + r * gh2);
  float hnew = (1.f - z) * n + z * hv;
  float s1 = hnew, s2 = hnew * hnew;
  #pragma unroll
  for (int m = 32; m >= 1; m >>= 1) { s1 += __shfl_xor(s1, m, 64); s2 += __shfl_xor(s2, m, 64); }
  if (lane == 0) { red1[wave] = s1; red2[wave] = s2; }
  __syncthreads();
  s1 = red1[0] + red1[1] + red1[2] + red1[3];
  s2 = red2[0] + red2[1] + red2[2] + red2[3];
  float mean = s1 * (1.f / D_);
  float rstd = rsqrtf(s2 * (1.f / D_) - mean * mean + LN_EPS_);
  ffs[t] = (hnew - mean) * rstd * gf[t] + bf[t];
  __syncthreads();
  {
    float h1a = b1[t], h2a = b1[D_ + t];
    #pragma unroll 8
    for (int d = 0; d < D_; ++d) {
      f16x2 wp = *(const f16x2*)&w1p[((size_t)d * 256 + t) * 2];
      float f0 = ffs[d];
      h1a = fmaf(f0, (float)wp[0], h1a);
      h2a = fmaf(f0, (float)wp[1], h2a);
    }
    hid[t] = fmaxf(h1a, 0.f); hid[D_ + t] = fmaxf(h2a, 0.f);
  }
  __syncthreads();
  float o;
  {
    float oa = b2[t], ob = 0.f;
    #pragma unroll 8
    for (int dd = 0; dd < 256; ++dd) {
      f16x2 wp = *(const f16x2*)&w2p[((size_t)dd * 256 + t) * 2];
      oa = fmaf(hid[2 * dd],     (float)wp[0], oa);
      ob = fmaf(hid[2 * dd + 1], (float)wp[1], ob);
    }
    o = oa + ob + hnew;
  }
  out[(size_t)row * D_ + t] = o;
  if (!want_qk) return;
  // next-iteration qkh = f16( LN_s(new slots) @ M )
  s1 = o; s2 = o * o;
  #pragma unroll
  for (int m = 32; m >= 1; m >>= 1) { s1 += __shfl_xor(s1, m, 64); s2 += __shfl_xor(s2, m, 64); }
  __syncthreads();
  if (lane == 0) { red1[wave] = s1; red2[wave] = s2; }
  __syncthreads();
  s1 = red1[0] + red1[1] + red1[2] + red1[3];
  s2 = red2[0] + red2[1] + red2[2] + red2[3];
  mean = s1 * (1.f / D_);
  rstd = rsqrtf(s2 * (1.f / D_) - mean * mean + LN_EPS_);
  ffs[t] = (o - mean) * rstd * gs[t] + bs[t];
  __syncthreads();
  {
    float a0 = 0.f, a1 = 0.f, a2 = 0.f, a3 = 0.f;
    #pragma unroll 8
    for (int d = 0; d < D_; d += 4) {
      a0 = fmaf(ffs[d],     M[(d)     * D_ + t], a0);
      a1 = fmaf(ffs[d + 1], M[(d + 1) * D_ + t], a1);
      a2 = fmaf(ffs[d + 2], M[(d + 2) * D_ + t], a2);
      a3 = fmaf(ffs[d + 3], M[(d + 3) * D_ + t], a3);
    }
    qkh[((size_t)bb * 16 + ii) * D_ + t] = (f16)(a0 + a1 + a2 + a3);
  }
}

extern "C" void kernel_launch(void* const* d_in, const int* in_sizes, int n_in,
                              void* d_out, int out_size, void* d_ws, size_t ws_size,
                              hipStream_t stream) {
  (void)in_sizes; (void)n_in; (void)out_size; (void)ws_size;
  const float* inputs = (const float*)d_in[0];
  const float* noise  = (const float*)d_in[1];
  const float* mu     = (const float*)d_in[2];
  const float* ls     = (const float*)d_in[3];
  const float* Wq     = (const float*)d_in[4];
  const float* Wk     = (const float*)d_in[5];
  const float* Wv     = (const float*)d_in[6];
  const float* gwi    = (const float*)d_in[7];
  const float* gwh    = (const float*)d_in[8];
  const float* gbi    = (const float*)d_in[9];
  const float* gbh    = (const float*)d_in[10];
  const float* w1     = (const float*)d_in[11];
  const float* b1     = (const float*)d_in[12];
  const float* w2     = (const float*)d_in[13];
  const float* b2     = (const float*)d_in[14];
  const float* gin    = (const float*)d_in[15];
  const float* bin    = (const float*)d_in[16];
  const float* gs     = (const float*)d_in[17];
  const float* bs     = (const float*)d_in[18];
  const float* gff    = (const float*)d_in[19];
  const float* bff    = (const float*)d_in[20];

  // workspace layout (all 16B-aligned offsets)
  const size_t KV = (size_t)B_ * N_ * D_;
  f16*   xh    = (f16*)d_ws;                       // 134 MB
  float* slots = (float*)(xh + KV);                // 131072 f32
  f16*   qkh   = (f16*)(slots + 131072);           // 262144 f16
  float* asp   = (float*)(qkh + 262144);           // 16384 f32
  float* urp   = asp + 16384;                      // 4.19M f32
  float* M     = urp + (size_t)B_ * NPART_ * NS_ * D_;  // 65536 f32
  f16*   gwp   = (f16*)(M + 65536);                // 524288 f16 (1 MB)
  f16*   w1p   = gwp + 524288;                     // 262144 f16
  f16*   w2p   = w1p + 262144;                     // 262144 f16

  k_setup<<<66816, 256, 0, stream>>>(inputs, gin, bin, xh, gwi, gwh, gwp,
                                     noise, mu, ls, slots, w1, w2, w1p, w2p);
  k_m<<<256, 256, 0, stream>>>(Wq, Wk, M);
  k_qk<<<512, 256, 0, stream>>>(slots, gs, bs, M, qkh);
  for (int it = 0; it < 4; ++it) {
    k_attn_upd<<<dim3(NPART_, B_), 256, 0, stream>>>(xh, qkh, urp, asp);
    float* outp = (it == 3) ? (float*)d_out : slots;
    k_gru_mlp<<<512, 256, 0, stream>>>(urp, asp, slots, Wv, gwp, gbi, gbh,
                                       w1p, b1, w2p, b2, gff, bff, gs, bs, M,
                                       (it < 3) ? 1 : 0, outp, qkh);
  }
}

// Round 25
// 472.172 us; speedup vs baseline: 1.0330x; 1.0330x over previous
//
#include <hip/hip_runtime.h>
#include <cstdint>

#define B_ 64
#define N_ 4096
#define D_ 256
#define NS_ 8
#define HID_ 512
#define TOK_ 128
#define NPART_ 32
#define EPS_ 1e-8f
#define SCALE_ 0.0625f
#define LN_EPS_ 1e-5f

typedef _Float16 f16;
typedef __attribute__((ext_vector_type(4))) _Float16 f16x4;
typedef __attribute__((ext_vector_type(8))) _Float16 f16x8;
typedef __attribute__((ext_vector_type(4))) float f32x4;

#define MFMA16(a, b, c) __builtin_amdgcn_mfma_f32_16x16x32_f16(a, b, c, 0, 0, 0)
#define GLOAD_LDS16(g, l) __builtin_amdgcn_global_load_lds( \
    (const __attribute__((address_space(1))) void*)(g),     \
    (__attribute__((address_space(3))) void*)(l), 16, 0, 0)

// ---------------- merged setup: xh LN-cast | WkX | GRU-wT cast | slots | w1/w2 cast ----
__global__ __launch_bounds__(256) void k_setup(
    const float* __restrict__ in, const float* __restrict__ gin,
    const float* __restrict__ bin, f16* __restrict__ xh,
    const float* __restrict__ Wk, float* __restrict__ WkX,
    const float* __restrict__ wi, const float* __restrict__ wh,
    f16* __restrict__ wiTh, f16* __restrict__ whTh,
    const float* __restrict__ noise, const float* __restrict__ mu,
    const float* __restrict__ ls, float* __restrict__ slots,
    const float* __restrict__ w1, const float* __restrict__ w2,
    f16* __restrict__ w1h, f16* __restrict__ w2h) {
  const int blk = blockIdx.x;
  const int t = threadIdx.x;
  if (blk < 65536) {
    const int wave = t >> 6, lane = t & 63;
    const size_t row = (size_t)blk * 4 + wave;
    const float* r = in + row * D_;
    float4 a = *(const float4*)(r + lane * 4);
    float s1 = a.x + a.y + a.z + a.w;
    float s2 = a.x * a.x + a.y * a.y + a.z * a.z + a.w * a.w;
    #pragma unroll
    for (int m = 32; m >= 1; m >>= 1) { s1 += __shfl_xor(s1, m, 64); s2 += __shfl_xor(s2, m, 64); }
    const float mean = s1 * (1.f / D_);
    const float rstd = rsqrtf(s2 * (1.f / D_) - mean * mean + LN_EPS_);
    float4 gg = *(const float4*)(gin + lane * 4);
    float4 bv = *(const float4*)(bin + lane * 4);
    f16x4 o;
    o[0] = (f16)((a.x - mean) * rstd * gg.x + bv.x);
    o[1] = (f16)((a.y - mean) * rstd * gg.y + bv.y);
    o[2] = (f16)((a.z - mean) * rstd * gg.z + bv.z);
    o[3] = (f16)((a.w - mean) * rstd * gg.w + bv.w);
    *(f16x4*)(xh + row * D_ + lane * 4) = o;
  } else if (blk < 65792) {
    const int e = blk - 65536;
    WkX[t * 256 + e] = Wk[e * 256 + t];
  } else if (blk < 66560) {
    const int idx = (blk - 65792) * 256 + t;
    const int o = idx >> 8, d = idx & 255;
    wiTh[d * 768 + o] = (f16)wi[idx];
    whTh[d * 768 + o] = (f16)wh[idx];
  } else if (blk < 67072) {
    const int idx = (blk - 66560) * 256 + t;
    const int d = idx & 255;
    slots[idx] = mu[d] + __expf(ls[d]) * noise[idx];
  } else if (blk < 67584) {
    const int idx = (blk - 67072) * 256 + t;
    w1h[idx] = (f16)w1[idx];
  } else {
    const int idx = (blk - 67584) * 256 + t;
    w2h[idx] = (f16)w2[idx];
  }
}

// ---------------- M[c][e] = SCALE * sum_d Wq[c][d] * WkX[d][e] ----------------
__global__ __launch_bounds__(256) void k_m(const float* __restrict__ Wq,
                                           const float* __restrict__ WkX,
                                           float* __restrict__ M) {
  __shared__ float wq[256];
  const int c = blockIdx.x, e = threadIdx.x;
  wq[e] = Wq[c * 256 + e];
  __syncthreads();
  float a0 = 0.f, a1 = 0.f, a2 = 0.f, a3 = 0.f;
  #pragma unroll 8
  for (int d = 0; d < 256; d += 4) {
    a0 = fmaf(wq[d],     WkX[(d)     * 256 + e], a0);
    a1 = fmaf(wq[d + 1], WkX[(d + 1) * 256 + e], a1);
    a2 = fmaf(wq[d + 2], WkX[(d + 2) * 256 + e], a2);
    a3 = fmaf(wq[d + 3], WkX[(d + 3) * 256 + e], a3);
  }
  M[c * 256 + e] = (a0 + a1 + a2 + a3) * SCALE_;
}

// ---------------- qkh = f16( LN(slots) @ M )  (once, before iter 0) ----------------
__global__ __launch_bounds__(256) void k_qk(const float* __restrict__ slots,
    const float* __restrict__ g, const float* __restrict__ b,
    const float* __restrict__ M, f16* __restrict__ qkh) {
  const int row = blockIdx.x;
  const int t = threadIdx.x;
  __shared__ float sl[256];
  __shared__ float red1[4], red2[4];
  float val = slots[(size_t)row * D_ + t];
  float s1 = val, s2 = val * val;
  #pragma unroll
  for (int m = 32; m >= 1; m >>= 1) { s1 += __shfl_xor(s1, m, 64); s2 += __shfl_xor(s2, m, 64); }
  int wave = t >> 6, lane = t & 63;
  if (lane == 0) { red1[wave] = s1; red2[wave] = s2; }
  __syncthreads();
  s1 = red1[0] + red1[1] + red1[2] + red1[3];
  s2 = red2[0] + red2[1] + red2[2] + red2[3];
  float mean = s1 * (1.f / D_);
  float rstd = rsqrtf(s2 * (1.f / D_) - mean * mean + LN_EPS_);
  sl[t] = (val - mean) * rstd * g[t] + b[t];
  __syncthreads();
  float a0 = 0.f, a1 = 0.f, a2 = 0.f, a3 = 0.f;
  #pragma unroll 8
  for (int d = 0; d < D_; d += 4) {
    a0 = fmaf(sl[d],     M[(d)     * D_ + t], a0);
    a1 = fmaf(sl[d + 1], M[(d + 1) * D_ + t], a1);
    a2 = fmaf(sl[d + 2], M[(d + 2) * D_ + t], a2);
    a3 = fmaf(sl[d + 3], M[(d + 3) * D_ + t], a3);
  }
  qkh[((size_t)(row >> 3) * 16 + (row & 7)) * D_ + t] = (f16)(a0 + a1 + a2 + a3);
}

// ---------------- MFMA attention -> partials, 256 thr, TOK_=128 ----------------
// wv_s TRANSPOSED to [slot][token]: phase B reads weights as uniform float4
// (broadcast) over 4 tokens -> LDS ops in the serial loop halved.
__global__ __launch_bounds__(256) void k_attn_upd(
    const f16* __restrict__ xh, const f16* __restrict__ qkh,
    float* __restrict__ urp, float* __restrict__ asp) {
  __shared__ __align__(16) f16 xt[TOK_ * 256];   // 64 KB
  __shared__ __align__(16) f16 qs[16 * 256];     // 8 KB (rows 8-15 pad)
  __shared__ __align__(16) float wv_s[NS_ * TOK_];  // 4 KB, [slot][token]
  const int b = blockIdx.y;
  const int blkx = blockIdx.x;
  const int jt = blkx * TOK_;
  const int part = b * NPART_ + blkx;
  const int tid = threadIdx.x;
  const int wave = tid >> 6, lane = tid & 63;

  // stage xt: async direct-to-LDS, source pre-swizzled, dest linear
  {
    const f16* src = xh + ((size_t)b * N_ + jt) * D_;
    #pragma unroll
    for (int i = 0; i < 16; ++i) {
      const int r = i * 8 + (tid >> 5), c = tid & 31;
      GLOAD_LDS16(src + r * 256 + ((c ^ (r & 7)) * 8), &xt[r * 256 + c * 8]);
    }
  }
  // stage qs (manual, swizzled dest)
  {
    const int r = tid >> 4, c0 = (tid & 15) * 2;
    const f16* src = qkh + ((size_t)b * 16 + r) * D_;
    *(f16x8*)&qs[r * 256 + ((c0)     ^ (r & 7)) * 8] = *(const f16x8*)(src + c0 * 8);
    *(f16x8*)&qs[r * 256 + ((c0 + 1) ^ (r & 7)) * 8] = *(const f16x8*)(src + c0 * 8 + 8);
  }
  __syncthreads();

  // phase A: MFMA dots; A-frags (qk) loaded once; 2 N-tiles per wave
  const int kg = lane >> 4;
  f16x8 afr[8];
  {
    const int arow = lane & 15;
    #pragma unroll
    for (int kk = 0; kk < 8; ++kk)
      afr[kk] = *(const f16x8*)&qs[arow * 256 + ((kk * 4 + kg) ^ (arow & 7)) * 8];
  }
  #pragma unroll
  for (int t2 = 0; t2 < 2; ++t2) {
    const int nt = wave * 2 + t2;
    const int tok = nt * 16 + (lane & 15);
    f32x4 acc = {0.f, 0.f, 0.f, 0.f};
    #pragma unroll
    for (int kk = 0; kk < 8; ++kk) {
      f16x8 bf = *(const f16x8*)&xt[tok * 256 + ((kk * 4 + kg) ^ (tok & 7)) * 8];
      acc = MFMA16(afr[kk], bf, acc);
    }
    float o0 = __shfl_xor(acc[0], 16, 64);
    float o1 = __shfl_xor(acc[1], 16, 64);
    float o2 = __shfl_xor(acc[2], 16, 64);
    float o3 = __shfl_xor(acc[3], 16, 64);
    if (lane < 32) {
      float m = fmaxf(fmaxf(fmaxf(acc[0], acc[1]), fmaxf(acc[2], acc[3])),
                      fmaxf(fmaxf(o0, o1), fmaxf(o2, o3)));
      float e0 = __expf(acc[0] - m), e1 = __expf(acc[1] - m);
      float e2 = __expf(acc[2] - m), e3 = __expf(acc[3] - m);
      float sm = e0 + e1 + e2 + e3;
      float so = __shfl_xor(sm, 16, 64);
      float inv = 1.f / (sm + so);
      const int sb = (lane >> 4) * 4;   // slot group 0 or 4
      wv_s[(sb + 0) * TOK_ + tok] = e0 * inv + EPS_;
      wv_s[(sb + 1) * TOK_ + tok] = e1 * inv + EPS_;
      wv_s[(sb + 2) * TOK_ + tok] = e2 * inv + EPS_;
      wv_s[(sb + 3) * TOK_ + tok] = e3 * inv + EPS_;
    }
  }
  __syncthreads();

  // phase B: wave -> slots (2w, 2w+1); lane -> d-quad; weights as float4 over 4 tokens
  {
    const int i0 = wave * 2;
    const int ch0 = lane >> 1, sub = (lane & 1) * 4;
    float a0[4] = {0.f, 0.f, 0.f, 0.f};
    float a1[4] = {0.f, 0.f, 0.f, 0.f};
    float s0 = 0.f, s1 = 0.f;
    #pragma unroll 4
    for (int j4 = 0; j4 < TOK_; j4 += 4) {
      float4 w0v = *(const float4*)&wv_s[i0 * TOK_ + j4];        // uniform broadcast
      float4 w1v = *(const float4*)&wv_s[(i0 + 1) * TOK_ + j4];  // uniform broadcast
      s0 += w0v.x + w0v.y + w0v.z + w0v.w;
      s1 += w1v.x + w1v.y + w1v.z + w1v.w;
      float w0a[4] = {w0v.x, w0v.y, w0v.z, w0v.w};
      float w1a[4] = {w1v.x, w1v.y, w1v.z, w1v.w};
      #pragma unroll
      for (int u = 0; u < 4; ++u) {
        const int j = j4 + u;
        f16x4 v = *(const f16x4*)&xt[j * 256 + (ch0 ^ (j & 7)) * 8 + sub];
        float vx = (float)v[0], vy = (float)v[1], vz = (float)v[2], vw = (float)v[3];
        a0[0] = fmaf(w0a[u], vx, a0[0]); a0[1] = fmaf(w0a[u], vy, a0[1]);
        a0[2] = fmaf(w0a[u], vz, a0[2]); a0[3] = fmaf(w0a[u], vw, a0[3]);
        a1[0] = fmaf(w1a[u], vx, a1[0]); a1[1] = fmaf(w1a[u], vy, a1[1]);
        a1[2] = fmaf(w1a[u], vz, a1[2]); a1[3] = fmaf(w1a[u], vw, a1[3]);
      }
    }
    float* u0 = urp + ((size_t)part * NS_ + i0) * D_ + lane * 4;
    *(float4*)(u0)      = make_float4(a0[0], a0[1], a0[2], a0[3]);
    *(float4*)(u0 + D_) = make_float4(a1[0], a1[1], a1[2], a1[3]);
    if (lane == 0) {
      asp[part * NS_ + i0]     = s0;
      asp[part * NS_ + i0 + 1] = s1;
    }
  }
}

// ---------------- GRU + LN + MLP + next-qk; reduces 32 partials; f16 weights ----------------
__global__ __launch_bounds__(256) void k_gru_mlp(
    const float* __restrict__ urp, const float* __restrict__ asp,
    const float* __restrict__ slots, const float* __restrict__ Wv,
    const f16* __restrict__ wiTh, const f16* __restrict__ whTh,
    const float* __restrict__ bi, const float* __restrict__ bh,
    const f16* __restrict__ w1h, const float* __restrict__ b1,
    const f16* __restrict__ w2h, const float* __restrict__ b2,
    const float* __restrict__ gf, const float* __restrict__ bf,
    const float* __restrict__ gs, const float* __restrict__ bs,
    const float* __restrict__ M,
    float* __restrict__ out, f16* __restrict__ qkh) {
  const int row = blockIdx.x;
  const int bb = row >> 3, ii = row & 7;
  const int t = threadIdx.x;
  __shared__ float urs[256], xs[256], hs[256], ffs[256], hid[512];
  __shared__ float red1[4], red2[4];
  const int wave = t >> 6, lane = t & 63;
  const float hv = slots[(size_t)row * D_ + t];
  hs[t] = hv;
  {
    float usum = 0.f;
    #pragma unroll 8
    for (int p = 0; p < NPART_; ++p)
      usum += urp[((size_t)(bb * NPART_ + p) * NS_ + ii) * D_ + t];
    urs[t] = usum;
  }
  {
    float ap = (t < NPART_) ? asp[(size_t)(bb * NPART_ + t) * NS_ + ii] : 0.f;
    #pragma unroll
    for (int m = 16; m >= 1; m >>= 1) ap += __shfl_xor(ap, m, 64);
    if (t == 0) red1[0] = ap;
  }
  __syncthreads();
  const float asv = red1[0];
  {
    const float ia = 1.f / asv;
    float u0 = 0.f, u1 = 0.f, u2 = 0.f, u3 = 0.f;
    #pragma unroll 8
    for (int e = 0; e < D_; e += 4) {
      u0 = fmaf(urs[e],     Wv[(size_t)(e)     * D_ + t], u0);
      u1 = fmaf(urs[e + 1], Wv[(size_t)(e + 1) * D_ + t], u1);
      u2 = fmaf(urs[e + 2], Wv[(size_t)(e + 2) * D_ + t], u2);
      u3 = fmaf(urs[e + 3], Wv[(size_t)(e + 3) * D_ + t], u3);
    }
    xs[t] = (u0 + u1 + u2 + u3) * ia;
  }
  __syncthreads();
  float gi0 = bi[t], gi1 = bi[D_ + t], gi2 = bi[2 * D_ + t];
  float gh0 = bh[t], gh1 = bh[D_ + t], gh2 = bh[2 * D_ + t];
  #pragma unroll 8
  for (int d = 0; d < D_; ++d) {
    const f16* wid = wiTh + d * 768;
    const f16* whd = whTh + d * 768;
    float xd = xs[d], hd = hs[d];
    gi0 = fmaf(xd, (float)wid[t], gi0);
    gi1 = fmaf(xd, (float)wid[D_ + t], gi1);
    gi2 = fmaf(xd, (float)wid[2 * D_ + t], gi2);
    gh0 = fmaf(hd, (float)whd[t], gh0);
    gh1 = fmaf(hd, (float)whd[D_ + t], gh1);
    gh2 = fmaf(hd, (float)whd[2 * D_ + t], gh2);
  }
  float r = 1.f / (1.f + __expf(-(gi0 + gh0)));
  float z = 1.f / (1.f + __expf(-(gi1 + gh1)));
  float n = tanhf(gi2 + r * gh2);
  float hnew = (1.f - z) * n + z * hv;
  float s1 = hnew, s2 = hnew * hnew;
  #pragma unroll
  for (int m = 32; m >= 1; m >>= 1) { s1 += __shfl_xor(s1, m, 64); s2 += __shfl_xor(s2, m, 64); }
  if (lane == 0) { red1[wave] = s1; red2[wave] = s2; }
  __syncthreads();
  s1 = red1[0] + red1[1] + red1[2] + red1[3];
  s2 = red2[0] + red2[1] + red2[2] + red2[3];
  float mean = s1 * (1.f / D_);
  float rstd = rsqrtf(s2 * (1.f / D_) - mean * mean + LN_EPS_);
  ffs[t] = (hnew - mean) * rstd * gf[t] + bf[t];
  __syncthreads();
  {
    float h1a = b1[t], h2a = b1[D_ + t], h1b = 0.f, h2b = 0.f;
    #pragma unroll 8
    for (int d = 0; d < D_; d += 2) {
      float f0 = ffs[d], f1 = ffs[d + 1];
      h1a = fmaf(f0, (float)w1h[(size_t)(d)     * HID_ + t],      h1a);
      h2a = fmaf(f0, (float)w1h[(size_t)(d)     * HID_ + D_ + t], h2a);
      h1b = fmaf(f1, (float)w1h[(size_t)(d + 1) * HID_ + t],      h1b);
      h2b = fmaf(f1, (float)w1h[(size_t)(d + 1) * HID_ + D_ + t], h2b);
    }
    hid[t] = fmaxf(h1a + h1b, 0.f); hid[D_ + t] = fmaxf(h2a + h2b, 0.f);
  }
  __syncthreads();
  float o;
  {
    float oa = b2[t], ob = 0.f;
    #pragma unroll 8
    for (int d = 0; d < HID_; d += 2) {
      oa = fmaf(hid[d],     (float)w2h[(size_t)(d)     * D_ + t], oa);
      ob = fmaf(hid[d + 1], (float)w2h[(size_t)(d + 1) * D_ + t], ob);
    }
    o = oa + ob + hnew;
  }
  out[(size_t)row * D_ + t] = o;
  s1 = o; s2 = o * o;
  #pragma unroll
  for (int m = 32; m >= 1; m >>= 1) { s1 += __shfl_xor(s1, m, 64); s2 += __shfl_xor(s2, m, 64); }
  __syncthreads();
  if (lane == 0) { red1[wave] = s1; red2[wave] = s2; }
  __syncthreads();
  s1 = red1[0] + red1[1] + red1[2] + red1[3];
  s2 = red2[0] + red2[1] + red2[2] + red2[3];
  mean = s1 * (1.f / D_);
  rstd = rsqrtf(s2 * (1.f / D_) - mean * mean + LN_EPS_);
  ffs[t] = (o - mean) * rstd * gs[t] + bs[t];
  __syncthreads();
  {
    float a0 = 0.f, a1 = 0.f, a2 = 0.f, a3 = 0.f;
    #pragma unroll 8
    for (int d = 0; d < D_; d += 4) {
      a0 = fmaf(ffs[d],     M[(d)     * D_ + t], a0);
      a1 = fmaf(ffs[d + 1], M[(d + 1) * D_ + t], a1);
      a2 = fmaf(ffs[d + 2], M[(d + 2) * D_ + t], a2);
      a3 = fmaf(ffs[d + 3], M[(d + 3) * D_ + t], a3);
    }
    qkh[((size_t)(row >> 3) * 16 + (row & 7)) * D_ + t] = (f16)(a0 + a1 + a2 + a3);
  }
}

extern "C" void kernel_launch(void* const* d_in, const int* in_sizes, int n_in,
                              void* d_out, int out_size, void* d_ws, size_t ws_size,
                              hipStream_t stream) {
  (void)in_sizes; (void)n_in; (void)out_size; (void)ws_size;
  const float* inputs = (const float*)d_in[0];
  const float* noise  = (const float*)d_in[1];
  const float* mu     = (const float*)d_in[2];
  const float* ls     = (const float*)d_in[3];
  const float* Wq     = (const float*)d_in[4];
  const float* Wk     = (const float*)d_in[5];
  const float* Wv     = (const float*)d_in[6];
  const float* gwi    = (const float*)d_in[7];
  const float* gwh    = (const float*)d_in[8];
  const float* gbi    = (const float*)d_in[9];
  const float* gbh    = (const float*)d_in[10];
  const float* w1     = (const float*)d_in[11];
  const float* b1     = (const float*)d_in[12];
  const float* w2     = (const float*)d_in[13];
  const float* b2     = (const float*)d_in[14];
  const float* gin    = (const float*)d_in[15];
  const float* bin    = (const float*)d_in[16];
  const float* gs     = (const float*)d_in[17];
  const float* bs     = (const float*)d_in[18];
  const float* gff    = (const float*)d_in[19];
  const float* bff    = (const float*)d_in[20];

  // workspace layout
  const size_t KV = (size_t)B_ * N_ * D_;
  f16*   xh    = (f16*)d_ws;                       // 134 MB
  float* slots = (float*)(xh + KV);
  f16*   qkh   = (f16*)(slots + 131072);
  float* asp   = (float*)(qkh + 262144);
  float* urp   = asp + 16384;
  float* WkX   = urp + (size_t)B_ * NPART_ * NS_ * D_;
  float* M     = WkX + 65536;
  f16*   wiTh  = (f16*)(M + 65536);
  f16*   whTh  = wiTh + 196608;
  f16*   w1h   = whTh + 196608;
  f16*   w2h   = w1h + 131072;

  k_setup<<<68096, 256, 0, stream>>>(inputs, gin, bin, xh, Wk, WkX,
                                     gwi, gwh, wiTh, whTh,
                                     noise, mu, ls, slots, w1, w2, w1h, w2h);
  k_m<<<256, 256, 0, stream>>>(Wq, WkX, M);
  k_qk<<<512, 256, 0, stream>>>(slots, gs, bs, M, qkh);
  for (int it = 0; it < 4; ++it) {
    k_attn_upd<<<dim3(NPART_, B_), 256, 0, stream>>>(xh, qkh, urp, asp);
    float* outp = (it == 3) ? (float*)d_out : slots;
    k_gru_mlp<<<512, 256, 0, stream>>>(urp, asp, slots, Wv, wiTh, whTh, gbi, gbh,
                                       w1h, b1, w2h, b2, gff, bff, gs, bs, M,
                                       outp, qkh);
  }
}